// Round 13
// baseline (377.491 us; speedup 1.0000x reference)
//
#include <hip/hip_runtime.h>

#define EPS 1e-5f

typedef __attribute__((ext_vector_type(8))) short s8v;
typedef __attribute__((ext_vector_type(4))) float f4v;

__device__ __forceinline__ float leakyf(float z){ return z >= 0.f ? z : 0.2f*z; }
__device__ __forceinline__ float siluf(float y){ return y / (1.f + __expf(-y)); }
__device__ __forceinline__ unsigned f2bfu(float f){
  unsigned u = __float_as_uint(f);
  return (u + 0x7FFFu + ((u>>16)&1u)) >> 16;
}
__device__ __forceinline__ unsigned short bfr(float f){ return (unsigned short)f2bfu(f); }
__device__ __forceinline__ float bf2f16(unsigned short s){ return __uint_as_float(((unsigned)s)<<16); }

// ---------------- zero scratch ----------------
__global__ __launch_bounds__(256) void k_zero(float* __restrict__ p, int n){
  int i = blockIdx.x*256 + threadIdx.x;
  if (i < n) p[i] = 0.f;
}

// ------- NT GEMM via split-bf16 MFMA, 64x64 tile, 4 waves, register prefetch -------
template<bool TRANSA, bool STATS, bool FULL4>
__global__ __launch_bounds__(256) void k_gemm(
    const float* __restrict__ A, int lda, long aStr,
    const float* __restrict__ A3, int lda3,
    const float* __restrict__ fAbuck, float invnA, int CA,
    const float* __restrict__ gA, const float* __restrict__ bA,
    const float* __restrict__ B0, const float* __restrict__ B1,
    const float* __restrict__ B2, const float* __restrict__ B3, int ldb, long bStr,
    float* __restrict__ C, int ldc, long cStr,
    float* __restrict__ C3, int ldc3,
    int K, float* __restrict__ buck, int statC, int statChanStr)
{
  __shared__ unsigned short Ah[2048], Al[2048], Bh[2048], Bl[2048];
  __shared__ float Ssum[STATS?64:4], Ssq[STATS?64:4];
  __shared__ float mrA[TRANSA?1024:4];
  const int z = blockIdx.z;
  const bool zAlt = (A3 != nullptr) && (z == 3);
  const float* Az = zAlt ? A3 : A + (long)z*aStr;
  const int ldaz = zAlt ? lda3 : lda;
  const float* Bb = (z==0?B0 : z==1?B1 : (z==2?B2:B3)) + (long)z*bStr;
  float* Cb = zAlt ? C3 : (C + (long)z*cStr);
  const int ldcz = zAlt ? ldc3 : ldc;
  const bool doStats = STATS && !zAlt;
  const int tid = threadIdx.x;
  const int bm = blockIdx.x*64, bn = blockIdx.y*64;
  const int wv = tid>>6, lane = tid&63;
  const int lm = lane&15, quad = lane>>4;
  if (doStats && tid<64){ Ssum[tid]=0.f; Ssq[tid]=0.f; }
  if (TRANSA){
    for (int c = tid; c < CA; c += 256){
      float s=0.f, q=0.f;
      for (int b=0;b<64;b++){ s += fAbuck[(long)b*2*CA + c]; q += fAbuck[(long)b*2*CA + CA + c]; }
      float m = s*invnA;
      float v = fmaxf(q*invnA - m*m, 0.f);
      mrA[c] = m; mrA[CA + c] = rsqrtf(v + EPS);
    }
    __syncthreads();
  }

  const int r0 = tid>>3, kg = tid&7;
  const int qk = kg>>1, j0 = (kg&1)*4;
  const int s0 = ((((r0>>4)  )*4 + qk)*16 + ((r0&15)^qk))*8 + j0;
  const int s1 = ((((r0>>4)+2)*4 + qk)*16 + ((r0&15)^qk))*8 + j0;
  const float* aP0 = Az + (long)(bm+r0)*ldaz + kg*4;
  const float* aP1 = aP0 + (long)32*ldaz;
  const float* bP0 = Bb + (long)(bn+r0)*ldb + kg*4;
  const float* bP1 = bP0 + (long)32*ldb;

  f4v acc[4];
  #pragma unroll
  for (int j=0;j<4;j++) acc[j] = (f4v){0.f,0.f,0.f,0.f};

  float4 a0 = *(const float4*)(aP0);
  float4 a1 = *(const float4*)(aP1);
  float4 b0 = *(const float4*)(bP0);
  float4 b1 = *(const float4*)(bP1);

  for (int k0=0; k0<K; k0+=32){
    float4 av0 = a0, av1 = a1;
    if (TRANSA){
      float4 m4 = *(const float4*)&mrA[k0 + kg*4];
      float4 r4 = *(const float4*)&mrA[CA + k0 + kg*4];
      float4 g4 = *(const float4*)(gA + k0 + kg*4);
      float4 b4 = *(const float4*)(bA + k0 + kg*4);
      av0.x = siluf((av0.x - m4.x)*r4.x*g4.x + b4.x);
      av0.y = siluf((av0.y - m4.y)*r4.y*g4.y + b4.y);
      av0.z = siluf((av0.z - m4.z)*r4.z*g4.z + b4.z);
      av0.w = siluf((av0.w - m4.w)*r4.w*g4.w + b4.w);
      av1.x = siluf((av1.x - m4.x)*r4.x*g4.x + b4.x);
      av1.y = siluf((av1.y - m4.y)*r4.y*g4.y + b4.y);
      av1.z = siluf((av1.z - m4.z)*r4.z*g4.z + b4.z);
      av1.w = siluf((av1.w - m4.w)*r4.w*g4.w + b4.w);
    }
    ushort4 h4, l4;
    h4.x=bfr(av0.x); l4.x=bfr(av0.x-bf2f16(h4.x));
    h4.y=bfr(av0.y); l4.y=bfr(av0.y-bf2f16(h4.y));
    h4.z=bfr(av0.z); l4.z=bfr(av0.z-bf2f16(h4.z));
    h4.w=bfr(av0.w); l4.w=bfr(av0.w-bf2f16(h4.w));
    *(ushort4*)&Ah[s0]=h4; *(ushort4*)&Al[s0]=l4;
    h4.x=bfr(av1.x); l4.x=bfr(av1.x-bf2f16(h4.x));
    h4.y=bfr(av1.y); l4.y=bfr(av1.y-bf2f16(h4.y));
    h4.z=bfr(av1.z); l4.z=bfr(av1.z-bf2f16(h4.z));
    h4.w=bfr(av1.w); l4.w=bfr(av1.w-bf2f16(h4.w));
    *(ushort4*)&Ah[s1]=h4; *(ushort4*)&Al[s1]=l4;
    h4.x=bfr(b0.x); l4.x=bfr(b0.x-bf2f16(h4.x));
    h4.y=bfr(b0.y); l4.y=bfr(b0.y-bf2f16(h4.y));
    h4.z=bfr(b0.z); l4.z=bfr(b0.z-bf2f16(h4.z));
    h4.w=bfr(b0.w); l4.w=bfr(b0.w-bf2f16(h4.w));
    *(ushort4*)&Bh[s0]=h4; *(ushort4*)&Bl[s0]=l4;
    h4.x=bfr(b1.x); l4.x=bfr(b1.x-bf2f16(h4.x));
    h4.y=bfr(b1.y); l4.y=bfr(b1.y-bf2f16(h4.y));
    h4.z=bfr(b1.z); l4.z=bfr(b1.z-bf2f16(h4.z));
    h4.w=bfr(b1.w); l4.w=bfr(b1.w-bf2f16(h4.w));
    *(ushort4*)&Bh[s1]=h4; *(ushort4*)&Bl[s1]=l4;
    __syncthreads();
    if (k0+32 < K){
      a0 = *(const float4*)(aP0 + k0+32);
      a1 = *(const float4*)(aP1 + k0+32);
      b0 = *(const float4*)(bP0 + k0+32);
      b1 = *(const float4*)(bP1 + k0+32);
    }
    const int soA = ((wv*4 + quad)*16 + (lm^quad))*8;
    s8v ah = *(const s8v*)&Ah[soA];
    s8v al = *(const s8v*)&Al[soA];
    #pragma unroll
    for (int j=0;j<4;j++){
      const int soB = ((j*4 + quad)*16 + (lm^quad))*8;
      s8v bh = *(const s8v*)&Bh[soB];
      s8v bl = *(const s8v*)&Bl[soB];
      acc[j] = __builtin_amdgcn_mfma_f32_16x16x32_bf16(ah, bh, acc[j], 0,0,0);
      acc[j] = __builtin_amdgcn_mfma_f32_16x16x32_bf16(ah, bl, acc[j], 0,0,0);
      acc[j] = __builtin_amdgcn_mfma_f32_16x16x32_bf16(al, bh, acc[j], 0,0,0);
      if (FULL4)
        acc[j] = __builtin_amdgcn_mfma_f32_16x16x32_bf16(al, bl, acc[j], 0,0,0);
    }
    __syncthreads();
  }
  #pragma unroll
  for (int rr=0;rr<4;rr++){
    float* cr = Cb + (long)(bm + wv*16 + quad*4 + rr)*ldcz + bn + lm;
    #pragma unroll
    for (int j=0;j<4;j++) cr[j*16] = acc[j][rr];
  }
  if (doStats){
    #pragma unroll
    for (int j=0;j<4;j++){
      float s=0.f, q=0.f;
      #pragma unroll
      for (int rr=0;rr<4;rr++){ float v = acc[j][rr]; s += v; q += v*v; }
      s += __shfl_xor(s,16,64); s += __shfl_xor(s,32,64);
      q += __shfl_xor(q,16,64); q += __shfl_xor(q,32,64);
      if (quad==0){ atomicAdd(&Ssum[j*16+lm], s); atomicAdd(&Ssq[j*16+lm], q); }
    }
    __syncthreads();
    if (tid < 64){
      int chan = statChanStr*z + bn + tid;
      float* bb = buck + (long)(blockIdx.x & 63)*2*statC;
      atomicAdd(&bb[chan], Ssum[tid]);
      atomicAdd(&bb[statC + chan], Ssq[tid]);
    }
  }
}

__global__ void k_finalize(const float* __restrict__ buck, int C, float invn, float* __restrict__ mr){
  int c = blockIdx.x*256 + threadIdx.x;
  if (c < C){
    float s=0,q=0;
    for (int b=0;b<64;b++){ s += buck[(long)b*2*C + c]; q += buck[(long)b*2*C + C + c]; }
    float m = s*invn;
    float v = fmaxf(q*invn - m*m, 0.f);
    mr[c] = m; mr[C+c] = rsqrtf(v + EPS);
  }
}

// ---------------- BN+leaky on raw qkv -> key, q|v, sq (folds QKV finalize; 8 rows/block) ----------------
__global__ __launch_bounds__(256) void k_apply_qkv(const float* __restrict__ raw, const float* __restrict__ bQKV,
    const float* __restrict__ gq, const float* __restrict__ bq,
    const float* __restrict__ gk, const float* __restrict__ bk,
    const float* __restrict__ gv, const float* __restrict__ bv,
    float* __restrict__ key, float* __restrict__ qv, float* __restrict__ sq){
  __shared__ float mrs[1536];
  __shared__ float red[4];
  const int tid = threadIdx.x;
  const int wv = tid>>6, lane = tid&63;
  for (int c = tid; c < 768; c += 256){
    float s=0.f, q=0.f;
    for (int b=0;b<64;b++){ s += bQKV[(long)b*1536 + c]; q += bQKV[(long)b*1536 + 768 + c]; }
    float m = s*(1.f/4096.f);
    float v = fmaxf(q*(1.f/4096.f) - m*m, 0.f);
    mrs[c] = m; mrs[768+c] = rsqrtf(v + EPS);
  }
  __syncthreads();
  const float gqv = gq[tid], bqv = bq[tid], gkv = gk[tid], bkv = bk[tid], gvv = gv[tid], bvv = bv[tid];
  for (int rr=0; rr<8; rr++){
    const long r = (long)blockIdx.x*8 + rr;
    const float* row = raw + r*768;
    float zq = row[tid], zk = row[256+tid], zv = row[512+tid];
    float yq = leakyf((zq - mrs[tid])*mrs[768+tid]*gqv + bqv);
    float yk = leakyf((zk - mrs[256+tid])*mrs[1024+tid]*gkv + bkv);
    float yv = leakyf((zv - mrs[512+tid])*mrs[1280+tid]*gvv + bvv);
    qv[r*512 + tid] = yq;
    key[r*256 + tid] = yk;
    qv[r*512 + 256 + tid] = yv;
    float kq = yk*yk;
    kq += __shfl_xor(kq,1,64); kq += __shfl_xor(kq,2,64);
    kq += __shfl_xor(kq,4,64); kq += __shfl_xor(kq,8,64);
    kq += __shfl_xor(kq,16,64); kq += __shfl_xor(kq,32,64);
    if (lane==0) red[wv] = kq;
    __syncthreads();
    if (tid==0) sq[r] = red[0]+red[1]+red[2]+red[3];
    __syncthreads();
  }
}

// ---------------- top-K (K=32): 2 waves/row (1024 cols each), min-4 buffer + tournament,
// ---------------- exact merge-path combine; fused z_pb stats split across the pair ----------------
__global__ __launch_bounds__(256) void k_topk(const float* __restrict__ G2, const float* __restrict__ sq,
    int* __restrict__ idxb, const float* __restrict__ P, float* __restrict__ bPB){
  __shared__ unsigned Ds[4][1024];          // dist bits per wave-half (16 KB)
  __shared__ unsigned long long M[4][32];   // per-wave sorted winners (1 KB)
  __shared__ int Wfin[2][32];               // merged winners per row
  const int wv = threadIdx.x >> 6, lane = threadIdx.x & 63;
  const int gw = blockIdx.x*4 + wv;
  const int row = gw >> 1, half = gw & 1;
  const int b = row >> 11, n = row & 2047;
  const float* Grow = G2 + (long)b*4194304 + (long)n*2048 + half*1024;
  const float* sqh  = sq + (long)b*2048 + half*1024;
  const float sqn = sq[(long)b*2048 + n];
  const unsigned mbase = half*1024;
  const unsigned long long SEN = 0xFFFFFFFFFFFFFFFFull;
  unsigned long long k0=SEN,k1=SEN,k2=SEN,k3=SEN;
  #pragma unroll
  for (int j=0;j<16;j++){
    int ml = lane + j*64;
    float d = sqn + sqh[ml] - 2.f*Grow[ml];
    unsigned u = __float_as_uint(d);
    u ^= ((unsigned)((int)u >> 31)) | 0x80000000u;
    Ds[wv][ml] = u;
    unsigned long long kk = ((unsigned long long)u << 32) | (mbase + ml);
    if (kk < k3){
      k3 = kk;
      if (k3 < k2){ unsigned long long t_=k2; k2=k3; k3=t_; }
      if (k2 < k1){ unsigned long long t_=k1; k1=k2; k2=t_; }
      if (k1 < k0){ unsigned long long t_=k0; k0=k1; k1=t_; }
    }
  }
  // 32-pop tournament over this wave's half
  for (int t=0;t<32;t++){
    unsigned long long v = k0;
    #pragma unroll
    for (int off=32; off; off>>=1){
      unsigned long long v2 = (unsigned long long)__shfl_xor((long long)v, off, 64);
      if (v2 < v) v = v2;
    }
    if (lane == 0) M[wv][t] = v;
    if (v == k0){               // unique owner
      int wl = ((int)(v & 0xFFFFFFFFull)) & 1023;
      Ds[wv][wl] = 0xFFFFFFFFu;
      k0=k1; k1=k2; k2=k3; k3=SEN;
      if (k0 == SEN){
        for (int j=0;j<16;j++){
          int ml = lane + j*64;
          unsigned u = Ds[wv][ml];
          if (u != 0xFFFFFFFFu){
            unsigned long long kk = ((unsigned long long)u << 32) | (mbase + ml);
            if (kk < k3){
              k3 = kk;
              if (k3 < k2){ unsigned long long t_=k2; k2=k3; k3=t_; }
              if (k2 < k1){ unsigned long long t_=k1; k1=k2; k2=t_; }
              if (k1 < k0){ unsigned long long t_=k0; k0=k1; k1=t_; }
            }
          }
        }
      }
    }
  }
  __syncthreads();
  // exact merge of the pair's two sorted 32-lists (merge-path rank); even waves only
  if ((wv & 1) == 0){
    const int rloc = wv >> 1;
    const unsigned long long* A  = M[wv];
    const unsigned long long* Bx = M[wv+1];
    const int t = lane & 31;
    const bool useA = lane < 32;
    unsigned long long e = useA ? A[t] : Bx[t];
    const unsigned long long* other = useA ? Bx : A;
    int lo = 0, hi = 32;
    while (lo < hi){ int mid = (lo+hi)>>1; if (other[mid] < e) lo = mid+1; else hi = mid; }
    int pos = t + lo;
    if (pos < 32){
      int m = (int)(e & 0xFFFFFFFFull);
      Wfin[rloc][pos] = m;
      idxb[(long)(blockIdx.x*2 + rloc)*32 + pos] = m;
    }
  }
  __syncthreads();
  // fused z_pb stats: each wave of the pair gathers 16 of its row's 32 neighbors
  const long bbase = (long)b << 11;
  const int c4 = lane*4;
  float4 pn = *(const float4*)(P + (long)row*256 + c4);
  float s0=0,s1=0,s2=0,s3=0,q0=0,q1=0,q2=0,q3=0;
  const int rloc = wv >> 1;
  #pragma unroll
  for (int t=0;t<16;t++){
    int g = Wfin[rloc][half*16 + t];
    float4 pg = *(const float4*)(P + (bbase + g)*256 + c4);
    float z0 = pg.x - pn.x, z1 = pg.y - pn.y, z2 = pg.z - pn.z, z3 = pg.w - pn.w;
    s0+=z0; q0+=z0*z0; s1+=z1; q1+=z1*z1;
    s2+=z2; q2+=z2*z2; s3+=z3; q3+=z3*z3;
  }
  float* bb = bPB + (long)(blockIdx.x & 63)*512;
  atomicAdd(&bb[c4+0], s0); atomicAdd(&bb[c4+1], s1);
  atomicAdd(&bb[c4+2], s2); atomicAdd(&bb[c4+3], s3);
  atomicAdd(&bb[256+c4+0], q0); atomicAdd(&bb[256+c4+1], q1);
  atomicAdd(&bb[256+c4+2], q2); atomicAdd(&bb[256+c4+3], q3);
}

// ---------------- E1 = (key[g]-q[n]+posb) @ We1^T via MFMA; fused stats ----------------
__global__ __launch_bounds__(256) void k_e1m(
    const float* __restrict__ key, const float* __restrict__ qv, const float* __restrict__ P,
    const int* __restrict__ idx, const float* __restrict__ mrPB,
    const float* __restrict__ gpb, const float* __restrict__ bpb,
    const float* __restrict__ We1, float* __restrict__ E1, float* __restrict__ buckE1)
{
  __shared__ unsigned short Ab[16384];
  __shared__ unsigned short Wb[8192];
  __shared__ float Ssum[32], Ssq[32];
  const int tid = threadIdx.x;
  const int wv = tid>>6, lane = tid&63;
  const int quad = lane>>4, lm = lane&15;
  const int bn0 = blockIdx.x*2;
  if (tid < 32){ Ssum[tid]=0.f; Ssq[tid]=0.f; }
  for (int e = tid; e < 8192; e += 256){
    int d = e >> 8, c = e & 255;
    int off = (((d>>4)*8 + (c>>5))*4 + ((c>>3)&3))*128 + (d&15)*8 + (c&7);
    Wb[off] = bfr(We1[e]);
  }
  {
    const int bn = bn0 + (wv>>1);
    const long base = (long)(bn >> 11) << 11;
    const int c4 = lane*4;
    float4 q4  = *(const float4*)(qv + (long)bn*512 + c4);
    float4 pn4 = *(const float4*)(P + (long)bn*256 + c4);
    float4 mp4 = *(const float4*)(mrPB + c4);
    float4 rp4 = *(const float4*)(mrPB + 256 + c4);
    float4 g4  = *(const float4*)(gpb + c4);
    float4 b4  = *(const float4*)(bpb + c4);
    const int ksc = c4>>5, quadc = (c4>>3)&3, jc = c4&7;
    for (int j = 0; j < 16; ++j){
      const int rloc = wv*16 + j;
      const int kk = rloc & 31;
      const int g = idx[bn*32 + kk];
      float4 kb = *(const float4*)(key + (base+g)*256 + c4);
      float4 pb = *(const float4*)(P + (base+g)*256 + c4);
      float o0 = kb.x - q4.x + leakyf((pb.x - pn4.x - mp4.x)*rp4.x*g4.x + b4.x);
      float o1 = kb.y - q4.y + leakyf((pb.y - pn4.y - mp4.y)*rp4.y*g4.y + b4.y);
      float o2 = kb.z - q4.z + leakyf((pb.z - pn4.z - mp4.z)*rp4.z*g4.z + b4.z);
      float o3 = kb.w - q4.w + leakyf((pb.w - pn4.w - mp4.w)*rp4.w*g4.w + b4.w);
      const int atile = rloc >> 4;
      const int slot = ((rloc & 15) ^ (ksc<<1) ^ quadc) & 15;
      const int off = ((atile*8 + ksc)*4 + quadc)*128 + slot*8 + jc;
      ushort4 u; u.x = bfr(o0); u.y = bfr(o1); u.z = bfr(o2); u.w = bfr(o3);
      *(ushort4*)&Ab[off] = u;
    }
  }
  __syncthreads();
  f4v acc0 = (f4v){0,0,0,0}, acc1 = (f4v){0,0,0,0};
  #pragma unroll
  for (int ks=0; ks<8; ks++){
    const int aslot = (lm ^ (ks<<1) ^ quad) & 15;
    s8v a  = *(const s8v*)&Ab[((wv*8 + ks)*4 + quad)*128 + aslot*8];
    s8v b0 = *(const s8v*)&Wb[((ks)*4 + quad)*128 + lm*8];
    s8v b1 = *(const s8v*)&Wb[((8 + ks)*4 + quad)*128 + lm*8];
    acc0 = __builtin_amdgcn_mfma_f32_16x16x32_bf16(a, b0, acc0, 0,0,0);
    acc1 = __builtin_amdgcn_mfma_f32_16x16x32_bf16(a, b1, acc1, 0,0,0);
  }
  {
    const int bn = bn0 + (wv>>1);
    const int mt = wv & 1;
    #pragma unroll
    for (int rr=0; rr<4; rr++){
      int krow = mt*16 + quad*4 + rr;
      float* o = E1 + ((long)bn*32 + krow)*32;
      o[lm]      = acc0[rr];
      o[16 + lm] = acc1[rr];
    }
  }
  float s0=0,q0=0,s1=0,q1=0;
  #pragma unroll
  for (int rr=0; rr<4; rr++){
    s0 += acc0[rr]; q0 += acc0[rr]*acc0[rr];
    s1 += acc1[rr]; q1 += acc1[rr]*acc1[rr];
  }
  s0 += __shfl_xor(s0,16,64); s0 += __shfl_xor(s0,32,64);
  q0 += __shfl_xor(q0,16,64); q0 += __shfl_xor(q0,32,64);
  s1 += __shfl_xor(s1,16,64); s1 += __shfl_xor(s1,32,64);
  q1 += __shfl_xor(q1,16,64); q1 += __shfl_xor(q1,32,64);
  if (quad == 0){
    atomicAdd(&Ssum[lm], s0);      atomicAdd(&Ssq[lm], q0);
    atomicAdd(&Ssum[16+lm], s1);   atomicAdd(&Ssq[16+lm], q1);
  }
  __syncthreads();
  if (tid < 32){
    float* bb = buckE1 + (long)(blockIdx.x & 63)*64;
    atomicAdd(&bb[tid], Ssum[tid]); atomicAdd(&bb[32+tid], Ssq[tid]);
  }
}

// ---------------- E2 = leaky(bn(E1)) @ We2^T via MFMA, in place; folded E1-finalize; fused stats ----------------
__global__ __launch_bounds__(256) void k_e2m(
    float* __restrict__ E, const float* __restrict__ bE1buck,
    const float* __restrict__ ge1, const float* __restrict__ be1,
    const float* __restrict__ We2, float* __restrict__ buckE2)
{
  __shared__ unsigned short Ab[8192];
  __shared__ unsigned short Wb[1024];
  __shared__ float Ssum[32], Ssq[32];
  __shared__ float mrE1s[64];
  const int tid = threadIdx.x;
  const int wv = tid>>6, lane = tid&63;
  const int quad = lane>>4, lm = lane&15;
  const long r0 = (long)blockIdx.x*256;
  if (tid < 32){
    Ssum[tid]=0.f; Ssq[tid]=0.f;
    float s=0.f, q=0.f;
    for (int b=0;b<64;b++){ s += bE1buck[b*64+tid]; q += bE1buck[b*64+32+tid]; }
    float m = s*(1.f/131072.f);
    float v = fmaxf(q*(1.f/131072.f) - m*m, 0.f);
    mrE1s[tid] = m; mrE1s[32+tid] = rsqrtf(v + EPS);
  }
  for (int e = tid; e < 1024; e += 256){
    int d = e>>5, c = e&31;
    int off = ((d>>4)*4 + ((c>>3)&3))*128 + (d&15)*8 + (c&7);
    Wb[off] = bfr(We2[e]);
  }
  __syncthreads();
  #pragma unroll
  for (int it=0; it<8; it++){
    int e = (tid + it*256)*4;
    int row = e>>5, c = e&31;
    float4 v = *(const float4*)(E + (r0 + row)*32 + c);
    float4 m4 = *(const float4*)&mrE1s[c];
    float4 r4 = *(const float4*)&mrE1s[32+c];
    float4 g4 = *(const float4*)(ge1 + c);
    float4 b4 = *(const float4*)(be1 + c);
    float o0 = leakyf((v.x - m4.x)*r4.x*g4.x + b4.x);
    float o1 = leakyf((v.y - m4.y)*r4.y*g4.y + b4.y);
    float o2 = leakyf((v.z - m4.z)*r4.z*g4.z + b4.z);
    float o3 = leakyf((v.w - m4.w)*r4.w*g4.w + b4.w);
    int quadc = (c>>3)&3, jc = c&7;
    int slot = ((row&15) ^ quadc) & 15;
    int off = ((row>>4)*4 + quadc)*128 + slot*8 + jc;
    ushort4 u; u.x=bfr(o0); u.y=bfr(o1); u.z=bfr(o2); u.w=bfr(o3);
    *(ushort4*)&Ab[off] = u;
  }
  __syncthreads();
  f4v acc0[4], acc1[4];
  #pragma unroll
  for (int i=0;i<4;i++){ acc0[i]=(f4v){0,0,0,0}; acc1[i]=(f4v){0,0,0,0}; }
  const int aslot = (lm ^ quad) & 15;
  s8v b0 = *(const s8v*)&Wb[(quad)*128 + lm*8];
  s8v b1 = *(const s8v*)&Wb[(4 + quad)*128 + lm*8];
  #pragma unroll
  for (int i=0;i<4;i++){
    const int atile = wv*4 + i;
    s8v a = *(const s8v*)&Ab[(atile*4 + quad)*128 + aslot*8];
    acc0[i] = __builtin_amdgcn_mfma_f32_16x16x32_bf16(a, b0, acc0[i], 0,0,0);
    acc1[i] = __builtin_amdgcn_mfma_f32_16x16x32_bf16(a, b1, acc1[i], 0,0,0);
  }
  __syncthreads();
  float s0=0,q0=0,s1=0,q1=0;
  #pragma unroll
  for (int i=0;i<4;i++){
    const int atile = wv*4 + i;
    #pragma unroll
    for (int rr=0; rr<4; rr++){
      long row = r0 + atile*16 + quad*4 + rr;
      float* o = E + row*32;
      o[lm]      = acc0[i][rr];
      o[16 + lm] = acc1[i][rr];
      s0 += acc0[i][rr]; q0 += acc0[i][rr]*acc0[i][rr];
      s1 += acc1[i][rr]; q1 += acc1[i][rr]*acc1[i][rr];
    }
  }
  s0 += __shfl_xor(s0,16,64); s0 += __shfl_xor(s0,32,64);
  q0 += __shfl_xor(q0,16,64); q0 += __shfl_xor(q0,32,64);
  s1 += __shfl_xor(s1,16,64); s1 += __shfl_xor(s1,32,64);
  q1 += __shfl_xor(q1,16,64); q1 += __shfl_xor(q1,32,64);
  if (quad == 0){
    atomicAdd(&Ssum[lm], s0);    atomicAdd(&Ssq[lm], q0);
    atomicAdd(&Ssum[16+lm], s1); atomicAdd(&Ssq[16+lm], q1);
  }
  __syncthreads();
  if (tid < 32){
    float* bb = buckE2 + (long)(blockIdx.x & 63)*64;
    atomicAdd(&bb[tid], Ssum[tid]); atomicAdd(&bb[32+tid], Ssq[tid]);
  }
}

// ---------------- softmax over k + attention + residual (4 bn/block, folded E2-finalize) ----------------
__global__ __launch_bounds__(256) void k_attn(
    const float* __restrict__ E2, const float* __restrict__ bE2buck,
    const float* __restrict__ ge2, const float* __restrict__ be2,
    const float* __restrict__ qv, const float* __restrict__ P, const int* __restrict__ idx,
    const float* __restrict__ mrPB, const float* __restrict__ gpb, const float* __restrict__ bpb,
    const float* __restrict__ xin, float* __restrict__ x2)
{
  __shared__ float L[4][32][33];
  __shared__ float mrE2s[64];
  const int tid = threadIdx.x;
  const int wv = tid>>6, lane = tid&63;
  if (tid < 32){
    float s=0.f, q=0.f;
    for (int b=0;b<64;b++){ s += bE2buck[b*64+tid]; q += bE2buck[b*64+32+tid]; }
    float m = s*(1.f/131072.f);
    float v = fmaxf(q*(1.f/131072.f) - m*m, 0.f);
    mrE2s[tid] = m; mrE2s[32+tid] = rsqrtf(v + EPS);
  }
  __syncthreads();
  const int bn = blockIdx.x*4 + wv;
  const long base = (long)(bn >> 11) << 11;
  for (int qq=0; qq<4; qq++){
    int e = lane*16 + qq*4;
    int k = e >> 5, g0 = e & 31;
    float4 v  = *(const float4*)(E2 + (long)bn*1024 + e);
    float4 m4 = *(const float4*)&mrE2s[g0];
    float4 r4 = *(const float4*)&mrE2s[32+g0];
    float4 g4 = *(const float4*)(ge2 + g0);
    float4 b4 = *(const float4*)(be2 + g0);
    L[wv][k][g0+0] = leakyf((v.x - m4.x)*r4.x*g4.x + b4.x);
    L[wv][k][g0+1] = leakyf((v.y - m4.y)*r4.y*g4.y + b4.y);
    L[wv][k][g0+2] = leakyf((v.z - m4.z)*r4.z*g4.z + b4.z);
    L[wv][k][g0+3] = leakyf((v.w - m4.w)*r4.w*g4.w + b4.w);
  }
  __syncthreads();
  {
    const int g = lane & 31, h = lane >> 5;
    float mx = -3.4e38f;
    for (int j=0;j<16;j++) mx = fmaxf(mx, L[wv][h*16+j][g]);
    mx = fmaxf(mx, __shfl_xor(mx, 32, 64));
    float sm = 0.f, ev[16];
    for (int j=0;j<16;j++){ float e_ = __expf(L[wv][h*16+j][g] - mx); ev[j] = e_; sm += e_; }
    sm += __shfl_xor(sm, 32, 64);
    float inv = 1.f/sm;
    for (int j=0;j<16;j++) L[wv][h*16+j][g] = ev[j]*inv;
  }
  __syncthreads();
  const int c4 = lane*4, gg = lane >> 1;
  float4 pn4 = *(const float4*)(P + (long)bn*256 + c4);
  float4 mp4 = *(const float4*)(mrPB + c4);
  float4 rp4 = *(const float4*)(mrPB + 256 + c4);
  float4 g4 = *(const float4*)(gpb + c4);
  float4 b4 = *(const float4*)(bpb + c4);
  float accv[4] = {0,0,0,0};
  const int* ir = idx + bn*32;
  for (int k=0;k<32;k++){
    int gi = ir[k];
    float4 vv = *(const float4*)(qv + (long)(base+gi)*512 + 256 + c4);
    float4 pp = *(const float4*)(P + (base+gi)*256 + c4);
    float w = L[wv][k][gg];
    float zh0 = (pp.x - pn4.x - mp4.x)*rp4.x*g4.x + b4.x;
    float zh1 = (pp.y - pn4.y - mp4.y)*rp4.y*g4.y + b4.y;
    float zh2 = (pp.z - pn4.z - mp4.z)*rp4.z*g4.z + b4.z;
    float zh3 = (pp.w - pn4.w - mp4.w)*rp4.w*g4.w + b4.w;
    accv[0] = fmaf(vv.x + leakyf(zh0), w, accv[0]);
    accv[1] = fmaf(vv.y + leakyf(zh1), w, accv[1]);
    accv[2] = fmaf(vv.z + leakyf(zh2), w, accv[2]);
    accv[3] = fmaf(vv.w + leakyf(zh3), w, accv[3]);
  }
  float4 x4 = *(const float4*)(xin + (long)bn*256 + c4);
  float4 o;
  o.x = x4.x + accv[0]; o.y = x4.y + accv[1];
  o.z = x4.z + accv[2]; o.w = x4.w + accv[3];
  *(float4*)(x2 + (long)bn*256 + c4) = o;
}

// ---------------- final: out = x2 + silu(bn(Zm2)), folded M2-finalize (8 rows/block) ----------------
__global__ __launch_bounds__(256) void k_final(const float* __restrict__ x2, const float* __restrict__ Zm2,
    const float* __restrict__ bM2buck, const float* __restrict__ gm, const float* __restrict__ bm,
    float* __restrict__ out){
  __shared__ float mrs[512];
  const int tid = threadIdx.x;
  {
    float s=0.f, q=0.f;
    for (int b=0;b<64;b++){ s += bM2buck[(long)b*512 + tid]; q += bM2buck[(long)b*512 + 256 + tid]; }
    float m = s*(1.f/4096.f);
    float v = fmaxf(q*(1.f/4096.f) - m*m, 0.f);
    mrs[tid] = m; mrs[256+tid] = rsqrtf(v + EPS);
  }
  __syncthreads();
  const float gmv = gm[tid], bmv = bm[tid];
  #pragma unroll
  for (int rr=0; rr<8; rr++){
    long r = (long)blockIdx.x*8 + rr;
    float z = Zm2[r*256 + tid];
    float y = (z - mrs[tid])*mrs[256+tid]*gmv + bmv;
    out[r*256 + tid] = x2[r*256 + tid] + siluf(y);
  }
}

extern "C" void kernel_launch(void* const* d_in, const int* in_sizes, int n_in,
                              void* d_out, int out_size, void* d_ws, size_t ws_size,
                              hipStream_t stream){
  (void)in_sizes; (void)n_in; (void)out_size; (void)ws_size;
  const float* x   = (const float*)d_in[0];
  const float* pos = (const float*)d_in[1];
  const float* Wq  = (const float*)d_in[2];
  const float* gq  = (const float*)d_in[3];
  const float* bq  = (const float*)d_in[4];
  const float* Wk  = (const float*)d_in[5];
  const float* gk  = (const float*)d_in[6];
  const float* bk  = (const float*)d_in[7];
  const float* Wv  = (const float*)d_in[8];
  const float* gv  = (const float*)d_in[9];
  const float* bv  = (const float*)d_in[10];
  const float* Wpb = (const float*)d_in[11];
  const float* gpb = (const float*)d_in[12];
  const float* bpb = (const float*)d_in[13];
  const float* We1 = (const float*)d_in[14];
  const float* ge1 = (const float*)d_in[15];
  const float* be1 = (const float*)d_in[16];
  const float* We2 = (const float*)d_in[17];
  const float* ge2 = (const float*)d_in[18];
  const float* be2 = (const float*)d_in[19];
  const float* Wm1 = (const float*)d_in[20];
  const float* gm1 = (const float*)d_in[21];
  const float* bm1 = (const float*)d_in[22];
  const float* Wm2 = (const float*)d_in[23];
  const float* gm2 = (const float*)d_in[24];
  const float* bm2 = (const float*)d_in[25];

  float* w     = (float*)d_ws;
  float* arena = w;                       // 4,194,304: rawQKV / E1->E2 / Zm1+Zm2
  float* key   = w + 4194304;             // 1,048,576
  float* P     = w + 5242880;             // 1,048,576
  float* x2    = w + 6291456;             // 1,048,576
  float* qv    = w + 7340032;             // 2,097,152
  float* sq    = w + 9437184;             // 4,096
  int*   idx   = (int*)(w + 9441280);     // 131,072 ints
  float* buck  = w + 9572352;             // 237,568
  float* mr    = w + 9809920;             // 3,712
  float* G2    = w + 9813632;             // 2 x 4,194,304 (both batch Grams)
  float* bQKV = buck;            float* bPB = buck + 98304;  float* bE1 = buck + 131072;
  float* bE2  = buck + 135168;   float* bM1 = buck + 139264; float* bM2 = buck + 204800;
  float* mrPB = mr + 1536;
  float* Zm1 = arena;
  float* Zm2 = arena + 2097152;

  k_zero<<<928,256,0,stream>>>(buck, 237568);
  // qkv (z=0..2, stats) + P (z=3) in one launch — FULL4: upstream of top-k
  k_gemm<false,true,true><<<dim3(64,4,4),256,0,stream>>>(
      x,256,0, pos,256, nullptr,0.f,0, nullptr,nullptr,
      Wq,Wk,Wv,Wpb,256,0, arena,768,256, P,256, 256, bQKV,768,256);
  k_apply_qkv<<<512,256,0,stream>>>(arena, bQKV, gq,bq,gk,bk,gv,bv, key, qv, sq);
  // both batch Grams in one launch — FULL4: the kNN distances themselves
  k_gemm<false,false,true><<<dim3(32,32,2),256,0,stream>>>(
      key,256,524288, nullptr,0, nullptr,0.f,0, nullptr,nullptr,
      key,key,key,nullptr,256,524288, G2,2048,4194304, nullptr,0, 256, nullptr,0,0);
  // topk: 2 waves per row, exact merge; fused z_pb stats
  k_topk<<<2048,256,0,stream>>>(G2, sq, idx, P, bPB);
  k_finalize<<<1,256,0,stream>>>(bPB, 256, 1.f/131072.f, mrPB);
  k_e1m<<<2048,256,0,stream>>>(key, qv, P, idx, mrPB, gpb, bpb, We1, arena, bE1);
  k_e2m<<<512,256,0,stream>>>(arena, bE1, ge1, be1, We2, bE2);
  k_attn<<<1024,256,0,stream>>>(arena, bE2, ge2, be2, qv, P, idx, mrPB, gpb, bpb, x, x2);
  k_gemm<false,true,false><<<dim3(64,8,1),256,0,stream>>>(
      x2,256,0, nullptr,0, nullptr,0.f,0, nullptr,nullptr,
      Wm1,Wm1,Wm1,nullptr,256,0, Zm1,512,0, nullptr,0, 256, bM1,512,0);
  k_gemm<true,true,false><<<dim3(64,4,1),256,0,stream>>>(
      Zm1,512,0, nullptr,0, bM1,1.f/4096.f,512, gm1,bm1,
      Wm2,Wm2,Wm2,nullptr,512,0, Zm2,256,0, nullptr,0, 512, bM2,256,0);
  k_final<<<512,256,0,stream>>>(x2, Zm2, bM2, gm2, bm2, (float*)d_out);
}